// Round 2
// baseline (624.728 us; speedup 1.0000x reference)
//
#include <hip/hip_runtime.h>
#include <hip/hip_bf16.h>

#define NN 100000
#define NE 1600000
#define ET (NE + NN)

typedef __hip_bfloat16 bf16;

__device__ __forceinline__ float bf2f(bf16 v){ return __bfloat162float(v); }

// ---------------- CSR build ----------------

__global__ void k_init_deg(int* __restrict__ deg){
    int i = blockIdx.x*256 + threadIdx.x;
    if(i < NN) deg[i] = 1;              // self loop
}

__global__ void k_hist(const int* __restrict__ dst, int* __restrict__ deg){
    int e = blockIdx.x*256 + threadIdx.x;
    if(e < NE) atomicAdd(&deg[dst[e]], 1);
}

// block of 256 threads scans 1024 elements
__global__ void k_scan1(const int* __restrict__ deg, int* __restrict__ rowst,
                        int* __restrict__ bsum){
    __shared__ int sh[256];
    int tid = threadIdx.x;
    int base = blockIdx.x*1024 + tid*4;
    int v0 = (base+0 < NN) ? deg[base+0] : 0;
    int v1 = (base+1 < NN) ? deg[base+1] : 0;
    int v2 = (base+2 < NN) ? deg[base+2] : 0;
    int v3 = (base+3 < NN) ? deg[base+3] : 0;
    int tot = v0+v1+v2+v3;
    sh[tid] = tot;
    __syncthreads();
    for(int off=1; off<256; off<<=1){
        int t = (tid>=off) ? sh[tid-off] : 0;
        __syncthreads();
        sh[tid] += t;
        __syncthreads();
    }
    int excl = sh[tid] - tot;
    if(tid==255) bsum[blockIdx.x] = sh[255];
    int run = excl;
    if(base+0 < NN) rowst[base+0] = run; run += v0;
    if(base+1 < NN) rowst[base+1] = run; run += v1;
    if(base+2 < NN) rowst[base+2] = run; run += v2;
    if(base+3 < NN) rowst[base+3] = run;
}

__global__ void k_scan2(int* __restrict__ bsum, int nb){
    __shared__ int sh[128];
    int tid = threadIdx.x;
    int v = (tid < nb) ? bsum[tid] : 0;
    sh[tid] = v;
    __syncthreads();
    for(int off=1; off<128; off<<=1){
        int t = (tid>=off) ? sh[tid-off] : 0;
        __syncthreads();
        sh[tid] += t;
        __syncthreads();
    }
    bsum[tid] = sh[tid] - v;            // exclusive
}

__global__ void k_scan3(int* __restrict__ rowst, const int* __restrict__ bsum,
                        int* __restrict__ cursor){
    int i = blockIdx.x*256 + threadIdx.x;
    if(i < NN){
        int v = rowst[i] + bsum[i >> 10];
        rowst[i] = v;
        cursor[i] = v;
    }
}

__global__ void k_scatter(const int* __restrict__ src, const int* __restrict__ dst,
                          int* __restrict__ cursor, int* __restrict__ edge_src){
    int e = blockIdx.x*256 + threadIdx.x;
    if(e < ET){
        int s, d;
        if(e < NE){ s = src[e]; d = dst[e]; }
        else      { s = e - NE; d = s; }
        int pos = atomicAdd(&cursor[d], 1);
        edge_src[pos] = s;
    }
}

// ---------------- h = x @ W, s_src = h@a_src, s_dst = h@a_dst ----------------
// one wave per node; lane = output feature; W column held in 64 VGPRs
// FPIN=1: input fp32 (x).  FPIN=0: input bf16 (t1 from layer 1).
// h written as bf16; ssrc/sdst from full fp32 accumulators.

template<int FPIN>
__global__ void __launch_bounds__(256) k_gemm(const void* __restrict__ xin,
        const float* __restrict__ W, const float* __restrict__ avs,
        const float* __restrict__ avd, bf16* __restrict__ hb,
        float* __restrict__ ssrc, float* __restrict__ sdst){
    int tid = threadIdx.x, wave = tid>>6, lane = tid&63;
    float Wreg[64];
    #pragma unroll
    for(int k=0;k<64;k++) Wreg[k] = W[k*64 + lane];
    float as = avs[lane], ad = avd[lane];
    int stride = gridDim.x*4;
    for(int node = blockIdx.x*4 + wave; node < NN; node += stride){
        float acc0=0.f, acc1=0.f, acc2=0.f, acc3=0.f;
        if(FPIN){
            const float4* xr = (const float4*)((const float*)xin + (size_t)node*64);
            #pragma unroll
            for(int q=0;q<16;q++){
                float4 xq = xr[q];      // wave-uniform (broadcast) load
                acc0 += xq.x*Wreg[4*q+0];
                acc1 += xq.y*Wreg[4*q+1];
                acc2 += xq.z*Wreg[4*q+2];
                acc3 += xq.w*Wreg[4*q+3];
            }
        } else {
            const uint4* xr = (const uint4*)((const bf16*)xin + (size_t)node*64);
            #pragma unroll
            for(int q=0;q<8;q++){
                uint4 pk = xr[q];       // 8 bf16, broadcast
                float x0 = __uint_as_float(pk.x << 16);
                float x1 = __uint_as_float(pk.x & 0xffff0000u);
                float x2 = __uint_as_float(pk.y << 16);
                float x3 = __uint_as_float(pk.y & 0xffff0000u);
                float x4 = __uint_as_float(pk.z << 16);
                float x5 = __uint_as_float(pk.z & 0xffff0000u);
                float x6 = __uint_as_float(pk.w << 16);
                float x7 = __uint_as_float(pk.w & 0xffff0000u);
                acc0 += x0*Wreg[8*q+0]; acc1 += x1*Wreg[8*q+1];
                acc2 += x2*Wreg[8*q+2]; acc3 += x3*Wreg[8*q+3];
                acc0 += x4*Wreg[8*q+4]; acc1 += x5*Wreg[8*q+5];
                acc2 += x6*Wreg[8*q+6]; acc3 += x7*Wreg[8*q+7];
            }
        }
        float acc = (acc0+acc1) + (acc2+acc3);
        hb[(size_t)node*64 + lane] = __float2bfloat16(acc);
        float ts = acc*as, td = acc*ad;
        #pragma unroll
        for(int m=32;m>=1;m>>=1){ ts += __shfl_xor(ts,m); td += __shfl_xor(td,m); }
        if(lane==0){ ssrc[node] = ts; sdst[node] = td; }
    }
}

// ---------------- per-node attention + aggregation ----------------
// one wave per destination node; lane = feature channel
// LAYER==1: out1b = tanh(agg + b) as bf16.  LAYER==2: out = (agg+b)@Wl + bl as fp32.

template<int LAYER>
__global__ void __launch_bounds__(256) k_aggregate(
        const int* __restrict__ rowst, const int* __restrict__ deg,
        const int* __restrict__ edge_src,
        const float* __restrict__ ssrc, const float* __restrict__ sdst,
        const bf16* __restrict__ hb,
        const float* __restrict__ bias, const float* __restrict__ Wl,
        const float* __restrict__ bl,
        bf16* __restrict__ out1b, float* __restrict__ outF){
    int wid  = (blockIdx.x*blockDim.x + threadIdx.x) >> 6;
    int lane = threadIdx.x & 63;
    if(wid >= NN) return;
    int rs = rowst[wid];
    int d  = deg[wid];
    float sd = sdst[wid];
    float acc = 0.f;

    if(d <= 64){
        // fast path: one edge per lane
        int   s = 0;
        float e = -1e30f;
        if(lane < d){
            s = edge_src[rs + lane];            // coalesced
            float t = ssrc[s] + sd;
            e = (t > 0.f) ? t : 0.2f*t;
        }
        float mx = e;
        #pragma unroll
        for(int m=32;m>=1;m>>=1) mx = fmaxf(mx, __shfl_xor(mx,m));
        float p = (lane < d) ? __expf(e - mx) : 0.f;
        float sm = p;
        #pragma unroll
        for(int m=32;m>=1;m>>=1) sm += __shfl_xor(sm,m);
        float alpha = p * (1.0f/(sm + 1e-16f));
        for(int j=0;j<d;j++){
            int   sj = __shfl(s, j);
            float aj = __shfl(alpha, j);
            acc += aj * bf2f(hb[(size_t)sj*64 + lane]);    // coalesced 128B/wave
        }
    } else {
        // generic path (degree > 64 — essentially never at Poisson(17))
        float lmax = -1e30f;
        for(int j=lane; j<d; j+=64){
            int sj = edge_src[rs+j];
            float t = ssrc[sj] + sd;
            t = (t > 0.f) ? t : 0.2f*t;
            lmax = fmaxf(lmax, t);
        }
        #pragma unroll
        for(int m=32;m>=1;m>>=1) lmax = fmaxf(lmax, __shfl_xor(lmax,m));
        float lsum = 0.f;
        for(int j=lane; j<d; j+=64){
            int sj = edge_src[rs+j];
            float t = ssrc[sj] + sd;
            t = (t > 0.f) ? t : 0.2f*t;
            lsum += __expf(t - lmax);
        }
        #pragma unroll
        for(int m=32;m>=1;m>>=1) lsum += __shfl_xor(lsum,m);
        float inv = 1.0f/(lsum + 1e-16f);
        for(int j=0;j<d;j++){
            int sj = edge_src[rs+j];
            float t = ssrc[sj] + sd;
            t = (t > 0.f) ? t : 0.2f*t;
            acc += __expf(t - lmax)*inv * bf2f(hb[(size_t)sj*64 + lane]);
        }
    }

    if(LAYER == 1){
        out1b[(size_t)wid*64 + lane] = __float2bfloat16(tanhf(acc + bias[lane]));
    } else {
        float v = acc + bias[lane];
        float t = v * Wl[lane];
        #pragma unroll
        for(int m=32;m>=1;m>>=1) t += __shfl_xor(t,m);
        if(lane==0) outF[wid] = t + bl[0];
    }
}

// ---------------- launch ----------------

extern "C" void kernel_launch(void* const* d_in, const int* in_sizes, int n_in,
                              void* d_out, int out_size, void* d_ws, size_t ws_size,
                              hipStream_t stream) {
    const float* x   = (const float*)d_in[0];
    const int*   ei  = (const int*)d_in[1];
    const float* W1  = (const float*)d_in[2];
    const float* as1 = (const float*)d_in[3];
    const float* ad1 = (const float*)d_in[4];
    const float* b1  = (const float*)d_in[5];
    const float* W2  = (const float*)d_in[6];
    const float* as2 = (const float*)d_in[7];
    const float* ad2 = (const float*)d_in[8];
    const float* b2  = (const float*)d_in[9];
    const float* Wl  = (const float*)d_in[10];
    const float* bl  = (const float*)d_in[11];
    float* out = (float*)d_out;

    const int* srcp = ei;
    const int* dstp = ei + NE;

    // workspace layout (16B-aligned blocks), total ~34.4 MB
    char* w = (char*)d_ws;
    int*   edge_src = (int*)w;      w += (size_t)ET*4;      //  6,800,000
    bf16*  hb       = (bf16*)w;     w += (size_t)NN*64*2;   // 12,800,000
    bf16*  t1b      = (bf16*)w;     w += (size_t)NN*64*2;   // 12,800,000
    int*   deg      = (int*)w;      w += (size_t)NN*4;
    int*   rowst    = (int*)w;      w += (size_t)NN*4;
    int*   cursor   = (int*)w;      w += (size_t)NN*4;
    float* ssrc     = (float*)w;    w += (size_t)NN*4;
    float* sdst     = (float*)w;    w += (size_t)NN*4;
    int*   bsum     = (int*)w;      w += 1024;

    const int nb1 = (NN + 255)/256;         // 391
    const int nbE = NE/256;                 // 6250
    const int nbS = (NN + 1023)/1024;       // 98
    const int nbT = (ET + 255)/256;         // 6641
    const int nbA = (NN + 3)/4;             // 25000

    k_init_deg<<<nb1, 256, 0, stream>>>(deg);
    k_hist   <<<nbE, 256, 0, stream>>>(dstp, deg);
    k_scan1  <<<nbS, 256, 0, stream>>>(deg, rowst, bsum);
    k_scan2  <<<1, 128, 0, stream>>>(bsum, nbS);
    k_scan3  <<<nb1, 256, 0, stream>>>(rowst, bsum, cursor);
    k_scatter<<<nbT, 256, 0, stream>>>(srcp, dstp, cursor, edge_src);

    // layer 1 (fp32 input x)
    k_gemm<1><<<1024, 256, 0, stream>>>((const void*)x, W1, as1, ad1, hb, ssrc, sdst);
    k_aggregate<1><<<nbA, 256, 0, stream>>>(rowst, deg, edge_src, ssrc, sdst, hb,
                                            b1, (const float*)nullptr, (const float*)nullptr,
                                            t1b, (float*)nullptr);
    // layer 2 (bf16 input t1) + final linear
    k_gemm<0><<<1024, 256, 0, stream>>>((const void*)t1b, W2, as2, ad2, hb, ssrc, sdst);
    k_aggregate<2><<<nbA, 256, 0, stream>>>(rowst, deg, edge_src, ssrc, sdst, hb,
                                            b2, Wl, bl,
                                            (bf16*)nullptr, out);
}

// Round 3
// 477.573 us; speedup vs baseline: 1.3081x; 1.3081x over previous
//
#include <hip/hip_runtime.h>
#include <hip/hip_bf16.h>

#define NN 100000
#define NE 1600000
#define ET (NE + NN)
#define NB 391          // buckets of 256 dst nodes
#define CAP 5120        // slots/bucket: mean 4352 (4096 rand + 256 self), +12 sigma
#define BSTRIDE 16      // global counter pad: 16 ints = 64B line each
#define EPB 8           // edges per thread in k_bin (2048/block)

typedef __hip_bfloat16 bf16;

__device__ __forceinline__ float bf2f(bf16 v){ return __bfloat162float(v); }

// ---------------- CSR build (bucketed, no random scatter) ----------------

__global__ void k_zero(int* __restrict__ bcnt){
    int i = blockIdx.x*256 + threadIdx.x;
    if(i < NB*BSTRIDE) bcnt[i] = 0;
}

// phase 1: bin edges by dst>>8; per-block LDS count -> one global atomic per
// bucket -> append packed (src<<8 | dst&255) at consecutive slots
__global__ void __launch_bounds__(256) k_bin(const int* __restrict__ src,
        const int* __restrict__ dst, int* __restrict__ bcnt,
        int* __restrict__ binbuf){
    __shared__ int cnt[NB];
    __shared__ int cur[NB];
    int t = threadIdx.x;
    for(int i=t;i<NB;i+=256) cnt[i]=0;
    __syncthreads();
    int e0 = blockIdx.x*(256*EPB);
    #pragma unroll
    for(int k=0;k<EPB;k++){
        int e = e0 + k*256 + t;
        if(e < ET){
            int d = (e < NE) ? dst[e] : (e - NE);
            atomicAdd(&cnt[d>>8], 1);
        }
    }
    __syncthreads();
    for(int i=t;i<NB;i+=256){
        int c = cnt[i];
        cur[i] = c ? atomicAdd(&bcnt[i*BSTRIDE], c) : 0;
    }
    __syncthreads();
    #pragma unroll
    for(int k=0;k<EPB;k++){
        int e = e0 + k*256 + t;
        if(e < ET){
            int s, d;
            if(e < NE){ s = src[e]; d = dst[e]; }
            else      { s = e - NE; d = s; }
            int b = d >> 8;
            int pos = atomicAdd(&cur[b], 1);
            if(pos < CAP) binbuf[b*CAP + pos] = (s << 8) | (d & 255);
        }
    }
}

// exclusive scan of bucket counts -> global bucket bases (1 block)
__global__ void k_scanb(const int* __restrict__ bcnt, int* __restrict__ bbase){
    __shared__ int sh[512];
    int t = threadIdx.x;
    int v = (t < NB) ? min(bcnt[t*BSTRIDE], CAP) : 0;
    sh[t] = v;
    __syncthreads();
    for(int off=1; off<512; off<<=1){
        int u = (t>=off) ? sh[t-off] : 0;
        __syncthreads();
        sh[t] += u;
        __syncthreads();
    }
    if(t < NB) bbase[t] = sh[t] - v;
}

// phase 2: one block per bucket; LDS hist + scan + local scatter; dense writes
__global__ void __launch_bounds__(256) k_build(const int* __restrict__ bcnt,
        const int* __restrict__ bbase, const int* __restrict__ binbuf,
        int* __restrict__ edge_src, int* __restrict__ rowst, int* __restrict__ deg){
    __shared__ int lsrc[CAP];
    __shared__ int ldeg[256];
    __shared__ int lscan[256];
    __shared__ int lcur[256];
    int b = blockIdx.x, t = threadIdx.x;
    int cnt  = min(bcnt[b*BSTRIDE], CAP);
    int base = bbase[b];
    ldeg[t] = 0;
    __syncthreads();
    for(int i=t;i<cnt;i+=256) atomicAdd(&ldeg[binbuf[b*CAP+i] & 255], 1);
    __syncthreads();
    int dv = ldeg[t];
    lscan[t] = dv;
    __syncthreads();
    for(int off=1; off<256; off<<=1){
        int u = (t>=off) ? lscan[t-off] : 0;
        __syncthreads();
        lscan[t] += u;
        __syncthreads();
    }
    int excl = lscan[t] - dv;
    lcur[t] = excl;
    int node = b*256 + t;
    if(node < NN){ rowst[node] = base + excl; deg[node] = dv; }
    __syncthreads();
    for(int i=t;i<cnt;i+=256){
        int ent = binbuf[b*CAP+i];
        int pos = atomicAdd(&lcur[ent & 255], 1);
        lsrc[pos] = ent >> 8;           // pos < cnt <= CAP
    }
    __syncthreads();
    for(int i=t;i<cnt;i+=256) edge_src[base+i] = lsrc[i];   // coalesced
}

// ---------------- h = x @ W, s_src = h@a_src, s_dst = h@a_dst ----------------
// one wave per node; lane = output feature; W column held in 64 VGPRs

template<int FPIN>
__global__ void __launch_bounds__(256) k_gemm(const void* __restrict__ xin,
        const float* __restrict__ W, const float* __restrict__ avs,
        const float* __restrict__ avd, bf16* __restrict__ hb,
        float* __restrict__ ssrc, float* __restrict__ sdst){
    int tid = threadIdx.x, wave = tid>>6, lane = tid&63;
    float Wreg[64];
    #pragma unroll
    for(int k=0;k<64;k++) Wreg[k] = W[k*64 + lane];
    float as = avs[lane], ad = avd[lane];
    int stride = gridDim.x*4;
    for(int node = blockIdx.x*4 + wave; node < NN; node += stride){
        float acc0=0.f, acc1=0.f, acc2=0.f, acc3=0.f;
        if(FPIN){
            const float4* xr = (const float4*)((const float*)xin + (size_t)node*64);
            #pragma unroll
            for(int q=0;q<16;q++){
                float4 xq = xr[q];      // wave-uniform (broadcast) load
                acc0 += xq.x*Wreg[4*q+0];
                acc1 += xq.y*Wreg[4*q+1];
                acc2 += xq.z*Wreg[4*q+2];
                acc3 += xq.w*Wreg[4*q+3];
            }
        } else {
            const uint4* xr = (const uint4*)((const bf16*)xin + (size_t)node*64);
            #pragma unroll
            for(int q=0;q<8;q++){
                uint4 pk = xr[q];       // 8 bf16, broadcast
                float x0 = __uint_as_float(pk.x << 16);
                float x1 = __uint_as_float(pk.x & 0xffff0000u);
                float x2 = __uint_as_float(pk.y << 16);
                float x3 = __uint_as_float(pk.y & 0xffff0000u);
                float x4 = __uint_as_float(pk.z << 16);
                float x5 = __uint_as_float(pk.z & 0xffff0000u);
                float x6 = __uint_as_float(pk.w << 16);
                float x7 = __uint_as_float(pk.w & 0xffff0000u);
                acc0 += x0*Wreg[8*q+0]; acc1 += x1*Wreg[8*q+1];
                acc2 += x2*Wreg[8*q+2]; acc3 += x3*Wreg[8*q+3];
                acc0 += x4*Wreg[8*q+4]; acc1 += x5*Wreg[8*q+5];
                acc2 += x6*Wreg[8*q+6]; acc3 += x7*Wreg[8*q+7];
            }
        }
        float acc = (acc0+acc1) + (acc2+acc3);
        hb[(size_t)node*64 + lane] = __float2bfloat16(acc);
        float ts = acc*as, td = acc*ad;
        #pragma unroll
        for(int m=32;m>=1;m>>=1){ ts += __shfl_xor(ts,m); td += __shfl_xor(td,m); }
        if(lane==0){ ssrc[node] = ts; sdst[node] = td; }
    }
}

// ---------------- per-node attention + aggregation ----------------
// one wave per destination node; lane = feature channel

template<int LAYER>
__global__ void __launch_bounds__(256) k_aggregate(
        const int* __restrict__ rowst, const int* __restrict__ deg,
        const int* __restrict__ edge_src,
        const float* __restrict__ ssrc, const float* __restrict__ sdst,
        const bf16* __restrict__ hb,
        const float* __restrict__ bias, const float* __restrict__ Wl,
        const float* __restrict__ bl,
        bf16* __restrict__ out1b, float* __restrict__ outF){
    int wid  = (blockIdx.x*blockDim.x + threadIdx.x) >> 6;
    int lane = threadIdx.x & 63;
    if(wid >= NN) return;
    int rs = rowst[wid];
    int d  = deg[wid];
    float sd = sdst[wid];
    float acc = 0.f;

    if(d <= 64){
        int   s = 0;
        float e = -1e30f;
        if(lane < d){
            s = edge_src[rs + lane];            // coalesced
            float t = ssrc[s] + sd;
            e = (t > 0.f) ? t : 0.2f*t;
        }
        float mx = e;
        #pragma unroll
        for(int m=32;m>=1;m>>=1) mx = fmaxf(mx, __shfl_xor(mx,m));
        float p = (lane < d) ? __expf(e - mx) : 0.f;
        float sm = p;
        #pragma unroll
        for(int m=32;m>=1;m>>=1) sm += __shfl_xor(sm,m);
        float alpha = p * (1.0f/(sm + 1e-16f));
        for(int j=0;j<d;j++){
            int   sj = __shfl(s, j);
            float aj = __shfl(alpha, j);
            acc += aj * bf2f(hb[(size_t)sj*64 + lane]);    // 128B/wave
        }
    } else {
        float lmax = -1e30f;
        for(int j=lane; j<d; j+=64){
            int sj = edge_src[rs+j];
            float t = ssrc[sj] + sd;
            t = (t > 0.f) ? t : 0.2f*t;
            lmax = fmaxf(lmax, t);
        }
        #pragma unroll
        for(int m=32;m>=1;m>>=1) lmax = fmaxf(lmax, __shfl_xor(lmax,m));
        float lsum = 0.f;
        for(int j=lane; j<d; j+=64){
            int sj = edge_src[rs+j];
            float t = ssrc[sj] + sd;
            t = (t > 0.f) ? t : 0.2f*t;
            lsum += __expf(t - lmax);
        }
        #pragma unroll
        for(int m=32;m>=1;m>>=1) lsum += __shfl_xor(lsum,m);
        float inv = 1.0f/(lsum + 1e-16f);
        for(int j=0;j<d;j++){
            int sj = edge_src[rs+j];
            float t = ssrc[sj] + sd;
            t = (t > 0.f) ? t : 0.2f*t;
            acc += __expf(t - lmax)*inv * bf2f(hb[(size_t)sj*64 + lane]);
        }
    }

    if(LAYER == 1){
        out1b[(size_t)wid*64 + lane] = __float2bfloat16(tanhf(acc + bias[lane]));
    } else {
        float v = acc + bias[lane];
        float t = v * Wl[lane];
        #pragma unroll
        for(int m=32;m>=1;m>>=1) t += __shfl_xor(t,m);
        if(lane==0) outF[wid] = t + bl[0];
    }
}

// ---------------- launch ----------------

extern "C" void kernel_launch(void* const* d_in, const int* in_sizes, int n_in,
                              void* d_out, int out_size, void* d_ws, size_t ws_size,
                              hipStream_t stream) {
    const float* x   = (const float*)d_in[0];
    const int*   ei  = (const int*)d_in[1];
    const float* W1  = (const float*)d_in[2];
    const float* as1 = (const float*)d_in[3];
    const float* ad1 = (const float*)d_in[4];
    const float* b1  = (const float*)d_in[5];
    const float* W2  = (const float*)d_in[6];
    const float* as2 = (const float*)d_in[7];
    const float* ad2 = (const float*)d_in[8];
    const float* b2  = (const float*)d_in[9];
    const float* Wl  = (const float*)d_in[10];
    const float* bl  = (const float*)d_in[11];
    float* out = (float*)d_out;

    const int* srcp = ei;
    const int* dstp = ei + NE;

    // workspace layout (~34.0 MB); binbuf aliases hb (dead before k_gemm writes)
    char* w = (char*)d_ws;
    int*   edge_src = (int*)w;      w += (size_t)ET*4;      //  6.8 MB
    bf16*  hb       = (bf16*)w;     w += (size_t)NN*64*2;   // 12.8 MB
    bf16*  t1b      = (bf16*)w;     w += (size_t)NN*64*2;   // 12.8 MB
    int*   rowst    = (int*)w;      w += (size_t)NN*4;
    int*   deg      = (int*)w;      w += (size_t)NN*4;
    float* ssrc     = (float*)w;    w += (size_t)NN*4;
    float* sdst     = (float*)w;    w += (size_t)NN*4;
    int*   bcnt     = (int*)w;      w += (size_t)NB*BSTRIDE*4;
    int*   bbase    = (int*)w;      w += (size_t)NB*4;
    int*   binbuf   = (int*)hb;     // NB*CAP*4 = 8.0 MB <= 12.8 MB

    const int nbZ   = (NB*BSTRIDE + 255)/256;
    const int nbBin = (ET + 256*EPB - 1)/(256*EPB);     // 831
    const int nbA   = (NN + 3)/4;                       // 25000

    k_zero <<<nbZ, 256, 0, stream>>>(bcnt);
    k_bin  <<<nbBin, 256, 0, stream>>>(srcp, dstp, bcnt, binbuf);
    k_scanb<<<1, 512, 0, stream>>>(bcnt, bbase);
    k_build<<<NB, 256, 0, stream>>>(bcnt, bbase, binbuf, edge_src, rowst, deg);

    // layer 1 (fp32 input x)
    k_gemm<1><<<1024, 256, 0, stream>>>((const void*)x, W1, as1, ad1, hb, ssrc, sdst);
    k_aggregate<1><<<nbA, 256, 0, stream>>>(rowst, deg, edge_src, ssrc, sdst, hb,
                                            b1, (const float*)nullptr, (const float*)nullptr,
                                            t1b, (float*)nullptr);
    // layer 2 (bf16 input t1) + final linear
    k_gemm<0><<<1024, 256, 0, stream>>>((const void*)t1b, W2, as2, ad2, hb, ssrc, sdst);
    k_aggregate<2><<<nbA, 256, 0, stream>>>(rowst, deg, edge_src, ssrc, sdst, hb,
                                            b2, Wl, bl,
                                            (bf16*)nullptr, out);
}